// Round 11
// baseline (202.364 us; speedup 1.0000x reference)
//
#include <hip/hip_runtime.h>
#include <hip/hip_bf16.h>

// HierarchicalEmbedding.
// out[t,:] = E1[fidx]*val + sum_{i<nd_eff} w[i]*Eint[dig_i]
//   lab: val=vals[t], nd_eff=0;  icd/atc: val=1.0, nd_eff=ndigits[t].
//
// R11: depth-4 gather pipeline (one token/thread/group, 16 groups; gather for
// g+4 issued at g => ~320cy cover > L2 latency). Prologue: meta threads load
// their token's 6 digits directly (3x int2) and pack in-register -> one
// barrier, no sDig. Guard-free stores in full blocks.

#define LM1   6
#define D     128
#define TPB   128
#define NGRP  16
#define DEPTH 4

typedef float nfloat4 __attribute__((ext_vector_type(4)));
typedef int   nint4   __attribute__((ext_vector_type(4)));
typedef int   nint2   __attribute__((ext_vector_type(2)));

template <bool B> struct BoolC { static constexpr bool value = B; };

__global__ __launch_bounds__(256, 6) void hier_emb_kernel(
    const int*   __restrict__ first_chars,
    const int*   __restrict__ digits,
    const int*   __restrict__ ndigits,
    const int*   __restrict__ mods,
    const float* __restrict__ vals,
    const float* __restrict__ E1,
    const float* __restrict__ Eint,
    const int*   __restrict__ kappa_p,
    float*       __restrict__ out,
    int n)
{
    __shared__ float sEint[10][D];   // 5 KB
    __shared__ nint4 sMeta[TPB];     // 2 KB: {fidx, dig4b, nd_eff, val_bits}

    const int tid  = threadIdx.x;
    const int tok0 = blockIdx.x * TPB;

    // --- Stage Eint: 320 float4; 256 threads -> 2 rounds ---
    {
        const nfloat4* src = reinterpret_cast<const nfloat4*>(Eint);
        nfloat4*       dst = reinterpret_cast<nfloat4*>(&sEint[0][0]);
        dst[tid] = src[tid];
        const int i2 = 256 + tid;
        if (i2 < (10 * D) / 4) dst[i2] = src[i2];
    }
    // --- Meta: threads 0..127 each build one token's int4 (digits direct) ---
    if (tid < TPB) {
        int tt = tok0 + tid; if (tt >= n) tt = n - 1;
        const int mod  = mods[tt];
        const int fc   = first_chars[tt];
        const int fidx = (mod == 0) ? fc + 5 : (mod == 1) ? fc * 2 + 5 : 52 + fc;
        const int nd   = (mod == 2) ? 0 : ndigits[tt];
        const float v  = (mod == 2) ? vals[tt] : 1.0f;
        // 6 digits: 3x int2 (8B-aligned: tt*24 % 8 == 0)
        const nint2* dp = reinterpret_cast<const nint2*>(digits + (size_t)tt * LM1);
        const nint2 d01 = dp[0], d23 = dp[1], d45 = dp[2];
        const int pd = d01.x | (d01.y << 4) | (d23.x << 8) | (d23.y << 12)
                     | (d45.x << 16) | (d45.y << 20);
        nint4 m; m.x = fidx; m.y = pd; m.z = nd; m.w = __float_as_int(v);
        sMeta[tid] = m;
    }

    // Position weights 1/(i+2)^kappa.
    const int k = *kappa_p;
    float w[LM1];
#pragma unroll
    for (int i = 0; i < LM1; ++i) {
        float p = 1.0f;
        const float b = (float)(i + 2);
        for (int j = 0; j < k; ++j) p *= b;
        w[i] = 1.0f / p;
    }

    __syncthreads();

    const int q4 = (tid & 31) * 4;     // float offset within the D=128 row
    const int h  = (tid >> 5) & 1;     // half-wave: adjacent tokens
    const int tb = (tid >> 6) * 32;    // wave's local token base

    const float* E1Q   = E1 + q4;
    const float* EintQ = &sEint[0][q4];
    float*       outQ  = out + q4;

    auto hot = [&](auto guard_c) {
        constexpr bool GUARD = decltype(guard_c)::value;
        nint4   m[DEPTH];
        nfloat4 b[DEPTH];
        // Prologue: issue gathers for groups 0..3.
#pragma unroll
        for (int p = 0; p < DEPTH; ++p) {
            m[p] = sMeta[tb + p * 2 + h];
            b[p] = *reinterpret_cast<const nfloat4*>(E1Q + (size_t)m[p].x * D);
        }
#pragma unroll
        for (int g = 0; g < NGRP; ++g) {
            const int s = g & (DEPTH - 1);     // static after unroll
            const nint4   mm = m[s];
            const nfloat4 bb = b[s];
            // Refill slot s with group g+DEPTH (gather issued ~4 bodies early).
            if (g + DEPTH < NGRP) {
                m[s] = sMeta[tb + (g + DEPTH) * 2 + h];
                b[s] = *reinterpret_cast<const nfloat4*>(
                           E1Q + (size_t)m[s].x * D);
            }
            nfloat4 acc = bb * __int_as_float(mm.w);
            const int nd = mm.z, pd = mm.y;
#pragma unroll
            for (int i = 0; i < LM1; ++i) {
                if (i < nd) {
                    const int dg = (pd >> (4 * i)) & 15;
                    acc += w[i] * *reinterpret_cast<const nfloat4*>(EintQ + dg * D);
                }
            }
            const int tok = tok0 + tb + g * 2 + h;
            if (!GUARD || tok < n) {
                __builtin_nontemporal_store(
                    acc, reinterpret_cast<nfloat4*>(outQ + (size_t)tok * D));
            }
        }
    };

    if (tok0 + TPB <= n) hot(BoolC<false>{});
    else                 hot(BoolC<true>{});
}

extern "C" void kernel_launch(void* const* d_in, const int* in_sizes, int n_in,
                              void* d_out, int out_size, void* d_ws, size_t ws_size,
                              hipStream_t stream) {
    const int*   first_chars = (const int*)  d_in[0];
    const int*   digits      = (const int*)  d_in[1];
    const int*   ndigits     = (const int*)  d_in[2];
    const int*   mods        = (const int*)  d_in[3];
    const float* vals        = (const float*)d_in[4];
    const float* E1          = (const float*)d_in[5];
    const float* Eint        = (const float*)d_in[6];
    const int*   kappa       = (const int*)  d_in[7];
    float*       out         = (float*)d_out;

    const int n    = in_sizes[0];                 // tokens
    const int grid = (n + TPB - 1) / TPB;         // 2048 blocks at N=262144

    hier_emb_kernel<<<grid, 256, 0, stream>>>(
        first_chars, digits, ndigits, mods, vals, E1, Eint, kappa, out, n);
}

// Round 13
// 162.608 us; speedup vs baseline: 1.2445x; 1.2445x over previous
//
#include <hip/hip_runtime.h>
#include <hip/hip_bf16.h>

// HierarchicalEmbedding.
// out[t,:] = E1[fidx]*val + sum_{i<nd_eff} w[i]*Eint[dig_i]
//   lab: val=vals[t], nd_eff=0;  icd/atc: val=1.0, nd_eff=ndigits[t].
//
// R13 == R12 resubmit (infra failure). R10 skeleton (best: ~39us) + ONE
// change: branchless batched digit reads. All 6 Eint rows read
// unconditionally (digits past nd are valid indices), weights masked to 0
// instead (wm[i] = i<nd ? w[i] : 0). Removes the divergent i<nd branch
// (two wave halves had different nd) and lets the compiler batch ds_reads
// -> LDS latency hidden once per token block, not per iteration. Two
// 3-read sub-batches cap VGPR peak.

#define LM1 6
#define D   128
#define TPB 128

typedef float nfloat4 __attribute__((ext_vector_type(4)));
typedef int   nint4   __attribute__((ext_vector_type(4)));

__global__ __launch_bounds__(256, 8) void hier_emb_kernel(
    const int*   __restrict__ first_chars,
    const int*   __restrict__ digits,
    const int*   __restrict__ ndigits,
    const int*   __restrict__ mods,
    const float* __restrict__ vals,
    const float* __restrict__ E1,
    const float* __restrict__ Eint,
    const int*   __restrict__ kappa_p,
    float*       __restrict__ out,
    int n)
{
    __shared__ float sEint[10][D];     // 5 KB
    __shared__ nint4 sMeta[TPB];       // 2 KB: {fidx, dig4b, nd_eff, val_bits}
    __shared__ int   sDig[TPB * LM1];  // 3 KB

    const int tid  = threadIdx.x;
    const int tok0 = blockIdx.x * TPB;

    // --- Stage Eint: 320 float4 ---
    {
        const nfloat4* src = reinterpret_cast<const nfloat4*>(Eint);
        nfloat4*       dst = reinterpret_cast<nfloat4*>(&sEint[0][0]);
        dst[tid] = src[tid];
        const int i2 = 256 + tid;
        if (i2 < (10 * D) / 4) dst[i2] = src[i2];
    }
    // --- Stage digits coalesced: 768 ints, 3 rounds ---
    {
        const long lim = (long)n * LM1;
#pragma unroll
        for (int r = 0; r < (TPB * LM1) / 256; ++r) {
            const int i = tid + r * 256;
            long gi = (long)tok0 * LM1 + i;
            if (gi >= lim) gi = lim - 1;
            sDig[i] = digits[gi];
        }
    }
    // --- Scalar metadata (threads 0..127, coalesced) ---
    if (tid < TPB) {
        int tt = tok0 + tid; if (tt >= n) tt = n - 1;
        const int mod  = mods[tt];
        const int fc   = first_chars[tt];
        const int fidx = (mod == 0) ? fc + 5 : (mod == 1) ? fc * 2 + 5 : 52 + fc;
        const int nd   = (mod == 2) ? 0 : ndigits[tt];
        const float v  = (mod == 2) ? vals[tt] : 1.0f;
        nint4 m; m.x = fidx; m.y = 0; m.z = nd; m.w = __float_as_int(v);
        sMeta[tid] = m;
    }

    // Position weights 1/(i+2)^kappa.
    const int k = *kappa_p;
    float w[LM1];
#pragma unroll
    for (int i = 0; i < LM1; ++i) {
        float p = 1.0f;
        const float b = (float)(i + 2);
        for (int j = 0; j < k; ++j) p *= b;
        w[i] = 1.0f / p;
    }

    __syncthreads();

    // --- Pack each token's 6 digits into 4-bit fields of sMeta[t].y ---
    if (tid < TPB) {
        int pd = 0;
#pragma unroll
        for (int i = 0; i < LM1; ++i) pd |= sDig[tid * LM1 + i] << (4 * i);
        reinterpret_cast<int*>(sMeta)[tid * 4 + 1] = pd;
    }
    __syncthreads();

    const int q4 = (tid & 31) * 4;       // float offset within the D=128 row
    const int h  = (tid >> 5) & 1;       // half-wave
    const int wv = tid >> 6;             // wave 0..3
    const int tb = wv * 32;              // wave's local token base

    const float* E1Q   = E1 + q4;
    const float* EintQ = &sEint[0][q4];
    float*       outQ  = out + q4;

    // Branchless per-token accumulate: 6 unconditional Eint reads (two
    // sub-batches of 3), weights masked by nd.
    auto accum = [&](const nint4 mm, const nfloat4 bb) -> nfloat4 {
        nfloat4 acc = bb * __int_as_float(mm.w);
        const int nd = mm.z, pd = mm.y;
        // sub-batch 1: digits 0..2
        {
            const nfloat4 e0 = *reinterpret_cast<const nfloat4*>(EintQ + ((pd >>  0) & 15) * D);
            const nfloat4 e1 = *reinterpret_cast<const nfloat4*>(EintQ + ((pd >>  4) & 15) * D);
            const nfloat4 e2 = *reinterpret_cast<const nfloat4*>(EintQ + ((pd >>  8) & 15) * D);
            acc += (0 < nd ? w[0] : 0.0f) * e0;
            acc += (1 < nd ? w[1] : 0.0f) * e1;
            acc += (2 < nd ? w[2] : 0.0f) * e2;
        }
        // sub-batch 2: digits 3..5
        {
            const nfloat4 e3 = *reinterpret_cast<const nfloat4*>(EintQ + ((pd >> 12) & 15) * D);
            const nfloat4 e4 = *reinterpret_cast<const nfloat4*>(EintQ + ((pd >> 16) & 15) * D);
            const nfloat4 e5 = *reinterpret_cast<const nfloat4*>(EintQ + ((pd >> 20) & 15) * D);
            acc += (3 < nd ? w[3] : 0.0f) * e3;
            acc += (4 < nd ? w[4] : 0.0f) * e4;
            acc += (5 < nd ? w[5] : 0.0f) * e5;
        }
        return acc;
    };

    // Prologue: group 0 metadata + gathers.
    nint4 m0 = sMeta[tb + h];
    nint4 m1 = sMeta[tb + h + 2];
    nfloat4 b0 = *reinterpret_cast<const nfloat4*>(E1Q + (size_t)m0.x * D);
    nfloat4 b1 = *reinterpret_cast<const nfloat4*>(E1Q + (size_t)m1.x * D);

#pragma unroll
    for (int g = 0; g < 8; ++g) {
        // Prefetch group g+1 (LDS meta -> 2 independent E1 gathers).
        nint4 p0, p1; nfloat4 c0, c1;
        if (g < 7) {
            const int ln = tb + (g + 1) * 4 + h;
            p0 = sMeta[ln];
            p1 = sMeta[ln + 2];
            c0 = *reinterpret_cast<const nfloat4*>(E1Q + (size_t)p0.x * D);
            c1 = *reinterpret_cast<const nfloat4*>(E1Q + (size_t)p1.x * D);
        }

        const int ltA = tb + g * 4 + h;
        // Token A
        {
            const nfloat4 acc = accum(m0, b0);
            const int tok = tok0 + ltA;
            if (tok < n)
                __builtin_nontemporal_store(
                    acc, reinterpret_cast<nfloat4*>(outQ + (size_t)tok * D));
        }
        // Token B (= A + 2)
        {
            const nfloat4 acc = accum(m1, b1);
            const int tok = tok0 + ltA + 2;
            if (tok < n)
                __builtin_nontemporal_store(
                    acc, reinterpret_cast<nfloat4*>(outQ + (size_t)tok * D));
        }
        m0 = p0; m1 = p1; b0 = c0; b1 = c1;
    }
}

extern "C" void kernel_launch(void* const* d_in, const int* in_sizes, int n_in,
                              void* d_out, int out_size, void* d_ws, size_t ws_size,
                              hipStream_t stream) {
    const int*   first_chars = (const int*)  d_in[0];
    const int*   digits      = (const int*)  d_in[1];
    const int*   ndigits     = (const int*)  d_in[2];
    const int*   mods        = (const int*)  d_in[3];
    const float* vals        = (const float*)d_in[4];
    const float* E1          = (const float*)d_in[5];
    const float* Eint        = (const float*)d_in[6];
    const int*   kappa       = (const int*)  d_in[7];
    float*       out         = (float*)d_out;

    const int n    = in_sizes[0];                 // tokens
    const int grid = (n + TPB - 1) / TPB;         // 2048 blocks at N=262144

    hier_emb_kernel<<<grid, 256, 0, stream>>>(
        first_chars, digits, ndigits, mods, vals, E1, Eint, kappa, out, n);
}